// Round 3
// baseline (145.095 us; speedup 1.0000x reference)
//
#include <hip/hip_runtime.h>

// GnnLayer: out[50000,64] = leaky_relu((h[idx]/dist).reshape(N,2048) @ W + bias)
// v4: request-count fix. Round-2 showed per-CU MLP is saturated (2x occupancy,
// same time) -> cut loop memory requests. Wave split kg8 x mg1: each of 8 waves
// computes ALL 64 nodes x K=256 slice, so each B (W-fragment) slice is read once
// per block (256KB vs v3's 512KB). A-gathers unchanged (algorithmic floor).
// 4-stage pairwise cross-wave K-reduction in LDS.
// ws layout: [0, 256KB) = W fragments f16; [256KB, +6.4MB) = h f16 [50000][64]

#define N_NODES 50000
#define KN      32
#define FIN     64
#define FOUT    64
#define MTILE   64

typedef __attribute__((ext_vector_type(4))) float    f32x4;
typedef __attribute__((ext_vector_type(8))) _Float16 f16x8;
typedef __attribute__((ext_vector_type(4))) _Float16 f16x4;

// Merged prep: blocks [0,64) convert W -> fragment-ordered f16; blocks [64,..)
// convert h fp32 -> f16 (coalesced float4 -> f16x4).
__global__ void k_prep(const float* __restrict__ w, _Float16* __restrict__ wf,
                       const float* __restrict__ h, _Float16* __restrict__ hb) {
    __shared__ float s_w[32 * 64];
    const int tid = threadIdx.x;
    if (blockIdx.x < 64) {
        // wf[kk*2048 + t*512 + lane*8 + i] = W[kk*32 + (lane>>4)*8 + i][t*16 + (lane&15)]
        const int kk = blockIdx.x;
        for (int p = tid; p < 32 * 64; p += 256)
            s_w[p] = w[kk * 32 * 64 + p];
        __syncthreads();
        const int t = tid >> 6, lane = tid & 63;
        const int lm = lane & 15, q = lane >> 4;
        f16x8 o;
        #pragma unroll
        for (int i = 0; i < 8; ++i)
            o[i] = (_Float16)s_w[(q * 8 + i) * 64 + t * 16 + lm];
        *(f16x8*)(wf + kk * 2048 + t * 512 + lane * 8) = o;
    } else {
        const int i = (blockIdx.x - 64) * 256 + tid;  // 800000 float4s
        float4 v = ((const float4*)h)[i];
        f16x4 o = { (_Float16)v.x, (_Float16)v.y, (_Float16)v.z, (_Float16)v.w };
        ((f16x4*)hb)[i] = o;
    }
}

__global__ __launch_bounds__(512, 2) void k_main(
        const _Float16* __restrict__ hf,    // f16 h [N][64]
        const float*    __restrict__ pos,   // [N][3]
        const int*      __restrict__ nidx,  // [N][32]
        const _Float16* __restrict__ wf,    // f16 W fragments
        const float*    __restrict__ bias,  // [64]
        float*          __restrict__ out)   // [N][64]
{
    __shared__ int2  s_e[KN * MTILE];     // [kn][m] {idx, scl bits}, 16 KB
    __shared__ float s_red[2 * 64 * 68];  // 2 reduction regions, 34 KB

    const int tid = threadIdx.x;
    const int m0  = blockIdx.x * MTILE;

    // Phase 0: per-edge {neighbor idx, 1/dist}. m = p&63 -> conflict-free writes.
    for (int p = tid; p < MTILE * KN; p += 512) {
        int m = p & 63, k = p >> 6;
        int node = m0 + m;
        int idx = 0; float scl = 0.f;
        if (node < N_NODES) {
            idx = nidx[node * KN + k];
            float dx = pos[node * 3 + 0] - pos[idx * 3 + 0];
            float dy = pos[node * 3 + 1] - pos[idx * 3 + 1];
            float dz = pos[node * 3 + 2] - pos[idx * 3 + 2];
            float sq = dx * dx + dy * dy + dz * dz;
            scl = (sq == 0.f) ? 2.0f : rsqrtf(sq);  // ref: dist=0.5 when sq==0
        }
        s_e[k * MTILE + m] = make_int2(idx, __float_as_int(scl));
    }
    __syncthreads();

    const int lane = tid & 63, kg = tid >> 6;   // wave kg: kn in [kg*4, kg*4+4)
    const int lm = lane & 15, q = lane >> 4;

    const _Float16* pb = wf + lane * 8;
    const int ebase = (kg * 4) * MTILE + lm;

    f32x4 acc[4][4] = {};  // [m-tile][n-tile]: 64 nodes x 64 cols, K-partial

    // Prologue: gather A-fragments for j=0.
    f16x8   A[4][2];
    _Float16 sc[4];
    {
        #pragma unroll
        for (int mt = 0; mt < 4; ++mt) {
            int2 e = s_e[ebase + mt * 16];
            const _Float16* pa = hf + e.x * FIN + q * 8;
            A[mt][0] = *(const f16x8*)pa;
            A[mt][1] = *(const f16x8*)(pa + 32);
            sc[mt] = (_Float16)__int_as_float(e.y);
        }
    }

    #pragma unroll
    for (int j = 0; j < 4; ++j) {
        // Prefetch next kn's gathers before this kn's MFMAs.
        f16x8   NA[4][2];
        _Float16 ns[4];
        if (j < 3) {
            #pragma unroll
            for (int mt = 0; mt < 4; ++mt) {
                int2 e = s_e[ebase + (j + 1) * MTILE + mt * 16];
                const _Float16* pa = hf + e.x * FIN + q * 8;
                NA[mt][0] = *(const f16x8*)pa;
                NA[mt][1] = *(const f16x8*)(pa + 32);
                ns[mt] = (_Float16)__int_as_float(e.y);
            }
        }

        const int kn = kg * 4 + j;
        #pragma unroll
        for (int jh = 0; jh < 2; ++jh) {
            const _Float16* pbb = pb + (kn * 2 + jh) * 2048;
            f16x8 b0 = *(const f16x8*)(pbb);
            f16x8 b1 = *(const f16x8*)(pbb + 512);
            f16x8 b2 = *(const f16x8*)(pbb + 1024);
            f16x8 b3 = *(const f16x8*)(pbb + 1536);
            #pragma unroll
            for (int mt = 0; mt < 4; ++mt) {
                f16x8 a = A[mt][jh] * sc[mt];   // v_pk_mul_f16 x4
                acc[mt][0] = __builtin_amdgcn_mfma_f32_16x16x32_f16(a, b0, acc[mt][0], 0, 0, 0);
                acc[mt][1] = __builtin_amdgcn_mfma_f32_16x16x32_f16(a, b1, acc[mt][1], 0, 0, 0);
                acc[mt][2] = __builtin_amdgcn_mfma_f32_16x16x32_f16(a, b2, acc[mt][2], 0, 0, 0);
                acc[mt][3] = __builtin_amdgcn_mfma_f32_16x16x32_f16(a, b3, acc[mt][3], 0, 0, 0);
            }
        }

        if (j < 3) {
            #pragma unroll
            for (int mt = 0; mt < 4; ++mt) {
                A[mt][0] = NA[mt][0]; A[mt][1] = NA[mt][1]; sc[mt] = ns[mt];
            }
        }
    }

    // 4-stage pairwise cross-wave K-reduction (8 partials -> 2 regions).
    // C/D layout: col = lane&15 (n), row = q*4 + r. Global row = mt*16 + row.
    float* reg = s_red + (kg & 1) * (64 * 68);
    if (kg < 2) {
        #pragma unroll
        for (int mt = 0; mt < 4; ++mt)
            #pragma unroll
            for (int t = 0; t < 4; ++t)
                #pragma unroll
                for (int r = 0; r < 4; ++r)
                    reg[(mt * 16 + q * 4 + r) * 68 + t * 16 + lm] = acc[mt][t][r];
    }
    __syncthreads();
    if (kg >= 2 && kg < 4) {
        #pragma unroll
        for (int mt = 0; mt < 4; ++mt)
            #pragma unroll
            for (int t = 0; t < 4; ++t)
                #pragma unroll
                for (int r = 0; r < 4; ++r)
                    reg[(mt * 16 + q * 4 + r) * 68 + t * 16 + lm] += acc[mt][t][r];
    }
    __syncthreads();
    if (kg >= 4 && kg < 6) {
        #pragma unroll
        for (int mt = 0; mt < 4; ++mt)
            #pragma unroll
            for (int t = 0; t < 4; ++t)
                #pragma unroll
                for (int r = 0; r < 4; ++r)
                    reg[(mt * 16 + q * 4 + r) * 68 + t * 16 + lm] += acc[mt][t][r];
    }
    __syncthreads();
    if (kg >= 6) {
        #pragma unroll
        for (int mt = 0; mt < 4; ++mt)
            #pragma unroll
            for (int t = 0; t < 4; ++t)
                #pragma unroll
                for (int r = 0; r < 4; ++r)
                    reg[(mt * 16 + q * 4 + r) * 68 + t * 16 + lm] += acc[mt][t][r];
    }
    __syncthreads();

    // Epilogue: region0 + region1 + bias, leaky_relu, coalesced f32x4 stores.
    const int row = tid >> 3, c0 = (tid & 7) * 8;
    const int node = m0 + row;
    if (node < N_NODES) {
        #pragma unroll
        for (int i = 0; i < 2; ++i) {
            int c = c0 + i * 4;
            f32x4 v0 = *(const f32x4*)(s_red + row * 68 + c);
            f32x4 v1 = *(const f32x4*)(s_red + 64 * 68 + row * 68 + c);
            f32x4 bb = *(const f32x4*)(bias + c);
            f32x4 o = v0 + v1 + bb;
            #pragma unroll
            for (int j = 0; j < 4; ++j) o[j] = o[j] > 0.f ? o[j] : 0.01f * o[j];
            *(f32x4*)(out + node * FOUT + c) = o;
        }
    }
}

extern "C" void kernel_launch(void* const* d_in, const int* in_sizes, int n_in,
                              void* d_out, int out_size, void* d_ws, size_t ws_size,
                              hipStream_t stream) {
    const float* h    = (const float*)d_in[0];
    const float* pos  = (const float*)d_in[1];
    const int*   nidx = (const int*)d_in[2];
    const float* w    = (const float*)d_in[3];
    const float* bias = (const float*)d_in[4];
    float* out = (float*)d_out;

    _Float16* wf = (_Float16*)d_ws;                      // 256 KB (fragment-ordered W)
    _Float16* hb = (_Float16*)((char*)d_ws + 262144);    // 6.4 MB (h in f16)

    k_prep<<<64 + (N_NODES * FIN / 4) / 256, 256, 0, stream>>>(w, wf, h, hb);
    k_main<<<(N_NODES + MTILE - 1) / MTILE, 512, 0, stream>>>(hb, pos, nidx, wf, bias, out);
}